// Round 10
// baseline (97.649 us; speedup 1.0000x reference)
//
#include <hip/hip_runtime.h>
#include <hip/hip_bf16.h>

#define K_ 20
#define KD_ 128
#define HID_ 256
#define NKP_ 100

using short8_t = __attribute__((ext_vector_type(8))) short;
using f32x4 = __attribute__((ext_vector_type(4))) float;

__device__ __forceinline__ unsigned short f2bf(float f) {
    union { __hip_bfloat16 h; unsigned short u; } c; c.h = __float2bfloat16(f); return c.u;
}
__device__ __forceinline__ float vexp(float x) { float r; asm("v_exp_f32 %0, %1" : "=v"(r) : "v"(x)); return r; }
__device__ __forceinline__ float vrcp(float x) { float r; asm("v_rcp_f32 %0, %1" : "=v"(r) : "v"(x)); return r; }
__device__ __forceinline__ float bf_lo(unsigned u) { return __uint_as_float(u << 16); }
__device__ __forceinline__ float bf_hi(unsigned u) { return __uint_as_float(u & 0xffff0000u); }

#define CEXP 2.885390081777927f   /* 2*log2(e) */

// src [KR][NC] f32 -> frag-major bf16 (MFMA 16x16x32 B-operand layout):
// frag f = n*(KR/32)+s, lane l, elem j = src[s*32+(l>>4)*8+j][n*16+(l&15)]
__global__ __launch_bounds__(256) void prep_frags(
    const float* __restrict__ W1, const float* __restrict__ M1,
    const float* __restrict__ M2, unsigned short* __restrict__ w1f,
    unsigned short* __restrict__ m1f, unsigned short* __restrict__ m2f)
{
    const int b = blockIdx.x;
    const float* src; unsigned short* dst; int nc, smask, nshift, ib;
    if (b < 128)      { src = W1; dst = w1f; nc = 256; smask = 3; nshift = 2; ib = b; }
    else if (b < 256) { src = M1; dst = m1f; nc = 256; smask = 3; nshift = 2; ib = b - 128; }
    else              { src = M2; dst = m2f; nc = 128; smask = 7; nshift = 3; ib = b - 256; }
    const int i = ib * 256 + threadIdx.x;
    const int j = i & 7, l = (i >> 3) & 63, f = i >> 9;
    const int s = f & smask, n = f >> nshift;
    const int k = s * 32 + (l >> 4) * 8 + j;
    const int col = n * 16 + (l & 15);
    dst[i] = f2bf(src[k * nc + col]);
}

// 4 samples/block, 4 waves. Wave w owns hidden cols [64w,64w+64) (B-frags in
// registers) and gathers sample w. 2 barrier-free passes write logit partials
// to LDS; ONE barrier; then wave w finishes sample w (softmax + wsum).
// launch_bounds(256,4): <=128 VGPRs -> 4 waves/SIMD (16 waves/CU; LDS ~22KB).
__global__ __launch_bounds__(256, 4) void cdm_attn(
    const int* __restrict__ stu_idx, const int* __restrict__ kp_idx,
    const int* __restrict__ kp_len, const float* __restrict__ emb,
    const unsigned short* __restrict__ w1f,
    const float* __restrict__ b1, const float* __restrict__ w2,
    const float* __restrict__ b2,
    float* __restrict__ out_att, unsigned short* __restrict__ wsum_g)
{
    const int tid = threadIdx.x, lane = tid & 63, w = tid >> 6;
    const int base = blockIdx.x * 4;

    __shared__ unsigned short vec_s[4][K_][KD_];   // 20 KB, 256B rows, swizzled
    __shared__ float lp_s[2][2][4][24];            // [pass][sampleInPass][wave][row]
    __shared__ float l0_s[4];
    __shared__ int   len_s[4];
    __shared__ float att_s[4][K_];                 // staged att weights

    // ---- index loads first (unconditional, always in-bounds) ----
    const int g = lane >> 4, c16 = lane & 15;
    const int gs = base + w;
    const int len = kp_len[gs];
    const long long eb = (long long)stu_idx[gs] * (NKP_ * KD_);
    int kpr[5];
#pragma unroll
    for (int it = 0; it < 5; ++it)
        kpr[it] = kp_idx[gs * K_ + it * 4 + g];

    // ---- emb gather (predicated rows), batched: wave w stages sample w ----
    {
        float4 va[5], vb[5];
#pragma unroll
        for (int it = 0; it < 5; ++it) {
            va[it] = make_float4(0.f, 0.f, 0.f, 0.f);
            vb[it] = make_float4(0.f, 0.f, 0.f, 0.f);
            const int r = it * 4 + g;
            if (r < len) {
                const float4* src = (const float4*)(emb + eb + (long long)kpr[it] * KD_) + c16 * 2;
                va[it] = src[0]; vb[it] = src[1];
            }
        }
        char* sb = (char*)&vec_s[w][0][0];
#pragma unroll
        for (int it = 0; it < 5; ++it) {
            const int r = it * 4 + g;
            short8_t pk;
            pk[0] = (short)f2bf(va[it].x); pk[1] = (short)f2bf(va[it].y);
            pk[2] = (short)f2bf(va[it].z); pk[3] = (short)f2bf(va[it].w);
            pk[4] = (short)f2bf(vb[it].x); pk[5] = (short)f2bf(vb[it].y);
            pk[6] = (short)f2bf(vb[it].z); pk[7] = (short)f2bf(vb[it].w);
            *(short8_t*)(sb + r * 256 + ((c16 * 16) ^ ((r & 7) << 4))) = pk;
        }
        if (lane == 0) len_s[w] = len;
    }

    // ---- W1 B-fragments (wave-owned n-slice) + epilogue constants ----
    short8_t Bf[4][4];
    {
        const short8_t* bfr = (const short8_t*)w1f;
#pragma unroll
        for (int nn = 0; nn < 4; ++nn)
#pragma unroll
            for (int s = 0; s < 4; ++s)
                Bf[nn][s] = bfr[((w * 4 + nn) * 4 + s) * 64 + lane];
    }
    float b1C[4], w2r[4], n2r[4];
#pragma unroll
    for (int nn = 0; nn < 4; ++nn) {
        const int c = (w * 4 + nn) * 16 + (lane & 15);
        b1C[nn] = b1[c] * CEXP;
        w2r[nn] = w2[c];
        n2r[nn] = -2.f * w2r[nn];
    }
    const float b2v = b2[0];

    // ---- logit0 partial (zero-vec logit) ----
    {
        float p = 0.f;
#pragma unroll
        for (int nn = 0; nn < 4; ++nn)
            p = fmaf(n2r[nn], vrcp(vexp(b1C[nn]) + 1.f), p + w2r[nn]);
#pragma unroll
        for (int m = 1; m <= 8; m <<= 1) p += __shfl_xor(p, m);
        if (lane == 0) l0_s[w] = p;
    }
    __syncthreads();
    const float logit0 = l0_s[0] + l0_s[1] + l0_s[2] + l0_s[3] + b2v;

    // ---- 2 barrier-free passes of 2 samples ----
#pragma unroll
    for (int p = 0; p < 2; ++p) {
        const int sp = 2 * p;
        const int lA = len_s[sp], lB = len_s[sp + 1];
        const bool need2 = (lA > 16) || (lB > 16);

        short8_t A0[4], A1[4];
        {
            const char* bA = (const char*)&vec_s[sp][0][0];
            const char* bB = (const char*)&vec_s[sp + 1][0][0];
            const int lr = lane & 15;
            const int rowb = lr * 256;
#pragma unroll
            for (int s = 0; s < 4; ++s) {
                const int colA = (s * 64 + (lane >> 4) * 16) ^ ((lr & 7) << 4);
                A0[s] = *(const short8_t*)(bA + rowb + colA);
                A1[s] = *(const short8_t*)(bB + rowb + colA);
            }
        }

        float lp0[4] = {0, 0, 0, 0}, lp1[4] = {0, 0, 0, 0};
#pragma unroll
        for (int nn = 0; nn < 4; ++nn) {
            f32x4 a0 = {0.f, 0.f, 0.f, 0.f}, a1 = {0.f, 0.f, 0.f, 0.f};
#pragma unroll
            for (int s = 0; s < 4; ++s) {
                a0 = __builtin_amdgcn_mfma_f32_16x16x32_bf16(A0[s], Bf[nn][s], a0, 0, 0, 0);
                a1 = __builtin_amdgcn_mfma_f32_16x16x32_bf16(A1[s], Bf[nn][s], a1, 0, 0, 0);
            }
            const float bc = b1C[nn], wv = w2r[nn], n2 = n2r[nn];
#pragma unroll
            for (int i = 0; i < 4; ++i) {
                lp0[i] = fmaf(n2, vrcp(vexp(fmaf(a0[i], CEXP, bc)) + 1.f), lp0[i] + wv);
                lp1[i] = fmaf(n2, vrcp(vexp(fmaf(a1[i], CEXP, bc)) + 1.f), lp1[i] + wv);
            }
        }
#pragma unroll
        for (int i = 0; i < 4; ++i) {
#pragma unroll
            for (int m = 1; m <= 8; m <<= 1) {
                lp0[i] += __shfl_xor(lp0[i], m);
                lp1[i] += __shfl_xor(lp1[i], m);
            }
        }
        if ((lane & 15) == 0) {
            const int gq = lane >> 4;
#pragma unroll
            for (int i = 0; i < 4; ++i) {
                lp_s[p][0][w][gq * 4 + i] = lp0[i];
                lp_s[p][1][w][gq * 4 + i] = lp1[i];
            }
        }

        if (need2) {
            short8_t A2[4];
            const int lr = lane & 15;
            const char* t2b = (const char*)&vec_s[sp + ((lr >> 2) & 1)][0][0] + (16 + (lr & 3)) * 256;
            const bool v2 = lr < 8;
            const short8_t z = {0, 0, 0, 0, 0, 0, 0, 0};
#pragma unroll
            for (int s = 0; s < 4; ++s) {
                const int colT = s * 64 + (lane >> 4) * 16;
                const short8_t t = *(const short8_t*)(t2b + (colT ^ ((lr & 3) << 4)));
                A2[s] = v2 ? t : z;
            }
            float lp2[4] = {0, 0, 0, 0};
#pragma unroll
            for (int nn = 0; nn < 4; ++nn) {
                f32x4 a2 = {0.f, 0.f, 0.f, 0.f};
#pragma unroll
                for (int s = 0; s < 4; ++s)
                    a2 = __builtin_amdgcn_mfma_f32_16x16x32_bf16(A2[s], Bf[nn][s], a2, 0, 0, 0);
                const float bc = b1C[nn], wv = w2r[nn], n2 = n2r[nn];
#pragma unroll
                for (int i = 0; i < 4; ++i)
                    lp2[i] = fmaf(n2, vrcp(vexp(fmaf(a2[i], CEXP, bc)) + 1.f), lp2[i] + wv);
            }
#pragma unroll
            for (int i = 0; i < 4; ++i) {
#pragma unroll
                for (int m = 1; m <= 8; m <<= 1) lp2[i] += __shfl_xor(lp2[i], m);
            }
            if ((lane & 15) == 0 && (lane >> 4) < 2) {
                const int gq = lane >> 4;
#pragma unroll
                for (int i = 0; i < 4; ++i) lp_s[p][gq][w][16 + i] = lp2[i];
            }
        }
    }
    __syncthreads();

    // ---- wave w finishes sample w: full-wave softmax + wsum + writes ----
    {
        const int p = w >> 1, hh = w & 1;
        const int lenS = len_s[w];
        float logit = -1e30f;
        if (lane < K_) {
            logit = (lane < lenS)
                ? b2v + lp_s[p][hh][0][lane] + lp_s[p][hh][1][lane]
                      + lp_s[p][hh][2][lane] + lp_s[p][hh][3][lane]
                : logit0;
        }
        float mx = logit;
#pragma unroll
        for (int m = 32; m >= 1; m >>= 1) mx = fmaxf(mx, __shfl_xor(mx, m));
        const float e = (lane < K_) ? vexp((logit - mx) * 1.44269504f) : 0.f;
        float sm = e;
#pragma unroll
        for (int m = 32; m >= 1; m >>= 1) sm += __shfl_xor(sm, m);
        const float attv = (lane < lenS) ? e * vrcp(sm) : 0.f;
        if (lane < K_) { att_s[w][lane] = attv; out_att[gs * K_ + lane] = attv; }

        // wsum: lane covers 2 dims; att from LDS (same-wave ordered)
        const char* vb2 = (const char*)&vec_s[w][0][0];
        float s0 = 0.f, s1 = 0.f;
        for (int k = 0; k < lenS; ++k) {
            const float av = att_s[w][k];
            const unsigned u = *(const unsigned*)(vb2 + k * 256 + ((lane * 4) ^ ((k & 7) << 4)));
            s0 = fmaf(av, bf_lo(u), s0);
            s1 = fmaf(av, bf_hi(u), s1);
        }
        const unsigned pk = (unsigned)f2bf(s0) | ((unsigned)f2bf(s1) << 16);
        *(unsigned*)(wsum_g + gs * KD_ + lane * 2) = pk;
    }
}

// MLP tail on MFMA: 32 samples/block, 512 threads (8 waves, n-split).
__global__ __launch_bounds__(512) void cdm_mlp(
    const unsigned short* __restrict__ wsum_g,
    const unsigned short* __restrict__ m1f, const unsigned short* __restrict__ m2f,
    const float* __restrict__ mb1, const float* __restrict__ mb2,
    const float* __restrict__ M3, const float* __restrict__ mb3,
    float* __restrict__ out_scores)
{
    const int tid = threadIdx.x, lane = tid & 63, w = tid >> 6;   // w in 0..7
    const int S0 = blockIdx.x * 32;
    const int lr = lane & 15, g = lane >> 4;

    __shared__ unsigned short h1_s[32][HID_];  // 16 KB, 512B rows, swizzled
    __shared__ float sc_s[8][32];              // 1 KB

    // ---- pass 1: h1 = relu(ws @ M1 + mb1); wave w owns cols [32w, 32w+32) ----
    short8_t Aw[2][4];
#pragma unroll
    for (int m = 0; m < 2; ++m)
#pragma unroll
        for (int s = 0; s < 4; ++s)
            Aw[m][s] = *(const short8_t*)(wsum_g + (S0 + m * 16 + lr) * KD_
                                          + s * 32 + g * 8);
    short8_t B1r[2][4];
    {
        const short8_t* bf1 = (const short8_t*)m1f;
#pragma unroll
        for (int nn = 0; nn < 2; ++nn)
#pragma unroll
            for (int s = 0; s < 4; ++s)
                B1r[nn][s] = bf1[((w * 2 + nn) * 4 + s) * 64 + lane];
    }
#pragma unroll
    for (int nn = 0; nn < 2; ++nn) {
        f32x4 c0 = {0.f, 0.f, 0.f, 0.f}, c1 = {0.f, 0.f, 0.f, 0.f};
#pragma unroll
        for (int s = 0; s < 4; ++s) {
            c0 = __builtin_amdgcn_mfma_f32_16x16x32_bf16(Aw[0][s], B1r[nn][s], c0, 0, 0, 0);
            c1 = __builtin_amdgcn_mfma_f32_16x16x32_bf16(Aw[1][s], B1r[nn][s], c1, 0, 0, 0);
        }
        const int col = (w * 2 + nn) * 16 + lr;
        const float bias = mb1[col];
#pragma unroll
        for (int i = 0; i < 4; ++i) {
            const int r0 = g * 4 + i;
            const int r1 = 16 + r0;
            *(unsigned short*)((char*)h1_s + r0 * 512 + ((2 * col) ^ ((r0 & 7) << 4)))
                = f2bf(fmaxf(c0[i] + bias, 0.f));
            *(unsigned short*)((char*)h1_s + r1 * 512 + ((2 * col) ^ ((r0 & 7) << 4)))
                = f2bf(fmaxf(c1[i] + bias, 0.f));
        }
    }
    __syncthreads();

    // ---- pass 2: h2 = relu(h1 @ M2 + mb2) fused M3; wave w owns cols [16w,16w+16) ----
    short8_t B2r[8];
    {
        const short8_t* bf2 = (const short8_t*)m2f;
#pragma unroll
        for (int s = 0; s < 8; ++s)
            B2r[s] = bf2[(w * 8 + s) * 64 + lane];
    }
    f32x4 d0 = {0.f, 0.f, 0.f, 0.f}, d1 = {0.f, 0.f, 0.f, 0.f};
#pragma unroll
    for (int s = 0; s < 8; ++s) {
        const int off = (s * 64 + g * 16) ^ ((lr & 7) << 4);
        const short8_t Ah0 = *(const short8_t*)((const char*)h1_s + lr * 512 + off);
        const short8_t Ah1 = *(const short8_t*)((const char*)h1_s + (16 + lr) * 512 + off);
        d0 = __builtin_amdgcn_mfma_f32_16x16x32_bf16(Ah0, B2r[s], d0, 0, 0, 0);
        d1 = __builtin_amdgcn_mfma_f32_16x16x32_bf16(Ah1, B2r[s], d1, 0, 0, 0);
    }
    {
        const int col = w * 16 + lr;
        const float bb = mb2[col], m3v = M3[col];
        float part0[4], part1[4];
#pragma unroll
        for (int i = 0; i < 4; ++i) {
            part0[i] = fmaxf(d0[i] + bb, 0.f) * m3v;
            part1[i] = fmaxf(d1[i] + bb, 0.f) * m3v;
        }
#pragma unroll
        for (int i = 0; i < 4; ++i) {
#pragma unroll
            for (int q = 1; q <= 8; q <<= 1) {
                part0[i] += __shfl_xor(part0[i], q);
                part1[i] += __shfl_xor(part1[i], q);
            }
        }
        if (lr == 0) {
#pragma unroll
            for (int i = 0; i < 4; ++i) {
                sc_s[w][g * 4 + i]      = part0[i];
                sc_s[w][16 + g * 4 + i] = part1[i];
            }
        }
    }
    __syncthreads();
    if (tid < 32) {
        const float sc = sc_s[0][tid] + sc_s[1][tid] + sc_s[2][tid] + sc_s[3][tid]
                       + sc_s[4][tid] + sc_s[5][tid] + sc_s[6][tid] + sc_s[7][tid] + mb3[0];
        out_scores[S0 + tid] = 1.f / (1.f + __expf(-sc));
    }
}

extern "C" void kernel_launch(void* const* d_in, const int* in_sizes, int n_in,
                              void* d_out, int out_size, void* d_ws, size_t ws_size,
                              hipStream_t stream) {
    const int*   stu = (const int*)d_in[0];
    const int*   kpi = (const int*)d_in[1];
    const int*   kpl = (const int*)d_in[2];
    const float* emb = (const float*)d_in[3];
    const float* W1  = (const float*)d_in[4];
    const float* b1  = (const float*)d_in[5];
    const float* w2  = (const float*)d_in[6];
    const float* b2  = (const float*)d_in[7];
    const float* M1  = (const float*)d_in[8];
    const float* mb1 = (const float*)d_in[9];
    const float* M2  = (const float*)d_in[10];
    const float* mb2 = (const float*)d_in[11];
    const float* M3  = (const float*)d_in[12];
    const float* mb3 = (const float*)d_in[13];
    const int B = in_sizes[0];

    float* out_scores = (float*)d_out;
    float* out_att    = out_scores + B;

    unsigned short* w1f  = (unsigned short*)d_ws;       // 64 KB
    unsigned short* m1f  = w1f + 32768;                 // 64 KB
    unsigned short* m2f  = m1f + 32768;                 // 64 KB
    unsigned short* wsum = m2f + 32768;                 // B*128 bf16 = 4 MB

    prep_frags<<<384, 256, 0, stream>>>(W1, M1, M2, w1f, m1f, m2f);
    cdm_attn<<<B / 4, 256, 0, stream>>>(stu, kpi, kpl, emb, w1f, b1, w2, b2,
                                        out_att, wsum);
    cdm_mlp<<<B / 32, 512, 0, stream>>>(wsum, m1f, m2f, mb1, mb2, M3, mb3, out_scores);
}

// Round 11
// 71.519 us; speedup vs baseline: 1.3654x; 1.3654x over previous
//
#include <hip/hip_runtime.h>
#include <hip/hip_bf16.h>

#define K_ 20
#define KD_ 128
#define HID_ 256
#define NKP_ 100

using short8_t = __attribute__((ext_vector_type(8))) short;
using f32x4 = __attribute__((ext_vector_type(4))) float;

__device__ __forceinline__ unsigned short f2bf(float f) {
    union { __hip_bfloat16 h; unsigned short u; } c; c.h = __float2bfloat16(f); return c.u;
}
__device__ __forceinline__ float vexp(float x) { float r; asm("v_exp_f32 %0, %1" : "=v"(r) : "v"(x)); return r; }
__device__ __forceinline__ float vrcp(float x) { float r; asm("v_rcp_f32 %0, %1" : "=v"(r) : "v"(x)); return r; }
__device__ __forceinline__ float bf_lo(unsigned u) { return __uint_as_float(u << 16); }
__device__ __forceinline__ float bf_hi(unsigned u) { return __uint_as_float(u & 0xffff0000u); }

#define CEXP 2.885390081777927f   /* 2*log2(e) */

// src [KR][NC] f32 -> frag-major bf16 (MFMA 16x16x32 B-operand layout):
// frag f = n*(KR/32)+s, lane l, elem j = src[s*32+(l>>4)*8+j][n*16+(l&15)]
__global__ __launch_bounds__(256) void prep_frags(
    const float* __restrict__ W1, const float* __restrict__ M1,
    const float* __restrict__ M2, unsigned short* __restrict__ w1f,
    unsigned short* __restrict__ m1f, unsigned short* __restrict__ m2f)
{
    const int b = blockIdx.x;
    const float* src; unsigned short* dst; int nc, smask, nshift, ib;
    if (b < 128)      { src = W1; dst = w1f; nc = 256; smask = 3; nshift = 2; ib = b; }
    else if (b < 256) { src = M1; dst = m1f; nc = 256; smask = 3; nshift = 2; ib = b - 128; }
    else              { src = M2; dst = m2f; nc = 128; smask = 7; nshift = 3; ib = b - 256; }
    const int i = ib * 256 + threadIdx.x;
    const int j = i & 7, l = (i >> 3) & 63, f = i >> 9;
    const int s = f & smask, n = f >> nshift;
    const int k = s * 32 + (l >> 4) * 8 + j;
    const int col = n * 16 + (l & 15);
    dst[i] = f2bf(src[k * nc + col]);
}

// 8 samples/block, 4 waves. Wave w owns hidden cols [64w,64w+64) (B-frags in
// registers). 4 barrier-free passes write per-pass logit partials to LDS;
// ONE barrier; then wave w finishes pass-w's two samples (softmax + wsum).
__global__ __launch_bounds__(256, 3) void cdm_attn(
    const int* __restrict__ stu_idx, const int* __restrict__ kp_idx,
    const int* __restrict__ kp_len, const float* __restrict__ emb,
    const unsigned short* __restrict__ w1f,
    const float* __restrict__ b1, const float* __restrict__ w2,
    const float* __restrict__ b2,
    float* __restrict__ out_att, unsigned short* __restrict__ wsum_g)
{
    const int tid = threadIdx.x, lane = tid & 63, w = tid >> 6;
    const int base = blockIdx.x * 8;

    __shared__ unsigned short vec_s[8][K_][KD_];   // 40 KB, 256B rows, swizzled
    __shared__ float lp_s[4][2][4][24];            // [pass][sample][wave][row], 3 KB
    __shared__ float l0_s[4];
    __shared__ int   len_s[8];
    __shared__ float att_s[8][K_];                 // staged att weights

    // ---- index loads first (unconditional, always in-bounds): longest chain ----
    const int g = lane >> 4, c16 = lane & 15;
    int lens[2]; long long eb[2]; int kpr[2][5];
#pragma unroll
    for (int h = 0; h < 2; ++h) {
        const int gs = base + 2 * w + h;
        lens[h] = kp_len[gs];
        eb[h] = (long long)stu_idx[gs] * (NKP_ * KD_);
#pragma unroll
        for (int it = 0; it < 5; ++it)
            kpr[h][it] = kp_idx[gs * K_ + it * 4 + g];
    }

    // ---- emb gather (predicated rows), batched ----
    {
        float4 va[10], vb[10];
#pragma unroll
        for (int h = 0; h < 2; ++h) {
#pragma unroll
            for (int it = 0; it < 5; ++it) {
                const int q = h * 5 + it;
                va[q] = make_float4(0.f, 0.f, 0.f, 0.f);
                vb[q] = make_float4(0.f, 0.f, 0.f, 0.f);
                const int r = it * 4 + g;
                if (r < lens[h]) {
                    const float4* src = (const float4*)(emb + eb[h] + (long long)kpr[h][it] * KD_) + c16 * 2;
                    va[q] = src[0]; vb[q] = src[1];
                }
            }
        }
#pragma unroll
        for (int h = 0; h < 2; ++h) {
            char* sb = (char*)&vec_s[2 * w + h][0][0];
#pragma unroll
            for (int it = 0; it < 5; ++it) {
                const int q = h * 5 + it;
                const int r = it * 4 + g;
                short8_t pk;
                pk[0] = (short)f2bf(va[q].x); pk[1] = (short)f2bf(va[q].y);
                pk[2] = (short)f2bf(va[q].z); pk[3] = (short)f2bf(va[q].w);
                pk[4] = (short)f2bf(vb[q].x); pk[5] = (short)f2bf(vb[q].y);
                pk[6] = (short)f2bf(vb[q].z); pk[7] = (short)f2bf(vb[q].w);
                *(short8_t*)(sb + r * 256 + ((c16 * 16) ^ ((r & 7) << 4))) = pk;
            }
        }
        if (lane == 0) { len_s[2 * w] = lens[0]; len_s[2 * w + 1] = lens[1]; }
    }

    // ---- W1 B-fragments (wave-owned n-slice) + epilogue constants ----
    short8_t Bf[4][4];
    {
        const short8_t* bfr = (const short8_t*)w1f;
#pragma unroll
        for (int nn = 0; nn < 4; ++nn)
#pragma unroll
            for (int s = 0; s < 4; ++s)
                Bf[nn][s] = bfr[((w * 4 + nn) * 4 + s) * 64 + lane];
    }
    float b1C[4], w2r[4], n2r[4];
#pragma unroll
    for (int nn = 0; nn < 4; ++nn) {
        const int c = (w * 4 + nn) * 16 + (lane & 15);
        b1C[nn] = b1[c] * CEXP;
        w2r[nn] = w2[c];
        n2r[nn] = -2.f * w2r[nn];
    }
    const float b2v = b2[0];

    // ---- logit0 partial (zero-vec logit) ----
    {
        float p = 0.f;
#pragma unroll
        for (int nn = 0; nn < 4; ++nn)
            p = fmaf(n2r[nn], vrcp(vexp(b1C[nn]) + 1.f), p + w2r[nn]);
#pragma unroll
        for (int m = 1; m <= 8; m <<= 1) p += __shfl_xor(p, m);
        if (lane == 0) l0_s[w] = p;
    }
    __syncthreads();
    const float logit0 = l0_s[0] + l0_s[1] + l0_s[2] + l0_s[3] + b2v;

    // ---- 4 barrier-free passes of 2 samples ----
#pragma unroll
    for (int p = 0; p < 4; ++p) {
        const int sp = 2 * p;
        const int lA = len_s[sp], lB = len_s[sp + 1];
        const bool need2 = (lA > 16) || (lB > 16);

        short8_t A0[4], A1[4];
        {
            const char* bA = (const char*)&vec_s[sp][0][0];
            const char* bB = (const char*)&vec_s[sp + 1][0][0];
            const int lr = lane & 15;
            const int rowb = lr * 256;
#pragma unroll
            for (int s = 0; s < 4; ++s) {
                const int colA = (s * 64 + (lane >> 4) * 16) ^ ((lr & 7) << 4);
                A0[s] = *(const short8_t*)(bA + rowb + colA);
                A1[s] = *(const short8_t*)(bB + rowb + colA);
            }
        }

        float lp0[4] = {0, 0, 0, 0}, lp1[4] = {0, 0, 0, 0};
#pragma unroll
        for (int nn = 0; nn < 4; ++nn) {
            f32x4 a0 = {0.f, 0.f, 0.f, 0.f}, a1 = {0.f, 0.f, 0.f, 0.f};
#pragma unroll
            for (int s = 0; s < 4; ++s) {
                a0 = __builtin_amdgcn_mfma_f32_16x16x32_bf16(A0[s], Bf[nn][s], a0, 0, 0, 0);
                a1 = __builtin_amdgcn_mfma_f32_16x16x32_bf16(A1[s], Bf[nn][s], a1, 0, 0, 0);
            }
            const float bc = b1C[nn], wv = w2r[nn], n2 = n2r[nn];
#pragma unroll
            for (int i = 0; i < 4; ++i) {
                lp0[i] = fmaf(n2, vrcp(vexp(fmaf(a0[i], CEXP, bc)) + 1.f), lp0[i] + wv);
                lp1[i] = fmaf(n2, vrcp(vexp(fmaf(a1[i], CEXP, bc)) + 1.f), lp1[i] + wv);
            }
        }
#pragma unroll
        for (int i = 0; i < 4; ++i) {
#pragma unroll
            for (int m = 1; m <= 8; m <<= 1) {
                lp0[i] += __shfl_xor(lp0[i], m);
                lp1[i] += __shfl_xor(lp1[i], m);
            }
        }
        if ((lane & 15) == 0) {
            const int gq = lane >> 4;
#pragma unroll
            for (int i = 0; i < 4; ++i) {
                lp_s[p][0][w][gq * 4 + i] = lp0[i];
                lp_s[p][1][w][gq * 4 + i] = lp1[i];
            }
        }

        if (need2) {
            short8_t A2[4];
            const int lr = lane & 15;
            const char* t2b = (const char*)&vec_s[sp + ((lr >> 2) & 1)][0][0] + (16 + (lr & 3)) * 256;
            const bool v2 = lr < 8;
            const short8_t z = {0, 0, 0, 0, 0, 0, 0, 0};
#pragma unroll
            for (int s = 0; s < 4; ++s) {
                const int colT = s * 64 + (lane >> 4) * 16;
                const short8_t t = *(const short8_t*)(t2b + (colT ^ ((lr & 3) << 4)));
                A2[s] = v2 ? t : z;
            }
            float lp2[4] = {0, 0, 0, 0};
#pragma unroll
            for (int nn = 0; nn < 4; ++nn) {
                f32x4 a2 = {0.f, 0.f, 0.f, 0.f};
#pragma unroll
                for (int s = 0; s < 4; ++s)
                    a2 = __builtin_amdgcn_mfma_f32_16x16x32_bf16(A2[s], Bf[nn][s], a2, 0, 0, 0);
                const float bc = b1C[nn], wv = w2r[nn], n2 = n2r[nn];
#pragma unroll
                for (int i = 0; i < 4; ++i)
                    lp2[i] = fmaf(n2, vrcp(vexp(fmaf(a2[i], CEXP, bc)) + 1.f), lp2[i] + wv);
            }
#pragma unroll
            for (int i = 0; i < 4; ++i) {
#pragma unroll
                for (int m = 1; m <= 8; m <<= 1) lp2[i] += __shfl_xor(lp2[i], m);
            }
            if ((lane & 15) == 0 && (lane >> 4) < 2) {
                const int gq = lane >> 4;
#pragma unroll
                for (int i = 0; i < 4; ++i) lp_s[p][gq][w][16 + i] = lp2[i];
            }
        }
    }
    __syncthreads();

    // ---- wave w finishes pass-w's samples: softmax + wsum + writes ----
    {
        const int j = lane & 31, hh = lane >> 5;
        const int smp = 2 * w + hh;
        const int gsS = base + smp;
        const int lenS = len_s[smp];
        float logit = -1e30f;
        if (j < K_) {
            logit = (j < lenS)
                ? b2v + lp_s[w][hh][0][j] + lp_s[w][hh][1][j]
                      + lp_s[w][hh][2][j] + lp_s[w][hh][3][j]
                : logit0;
        }
        float mx = logit;
#pragma unroll
        for (int m = 16; m >= 1; m >>= 1) mx = fmaxf(mx, __shfl_xor(mx, m, 32));
        const float e = (j < K_) ? vexp((logit - mx) * 1.44269504f) : 0.f;
        float sm = e;
#pragma unroll
        for (int m = 16; m >= 1; m >>= 1) sm += __shfl_xor(sm, m, 32);
        const float attv = (j < lenS) ? e * vrcp(sm) : 0.f;
        if (j < K_) { att_s[smp][j] = attv; out_att[gsS * K_ + j] = attv; }

        // wsum: lane covers 4 dims of its sample; att from LDS (same-wave ordered)
        const int d0 = (lane & 31) * 4;
        const char* vb2 = (const char*)&vec_s[smp][0][0];
        const int lm = max(len_s[2 * w], len_s[2 * w + 1]);
        float s0 = 0.f, s1 = 0.f, s2 = 0.f, s3 = 0.f;
        for (int k = 0; k < lm; ++k) {
            const float av = att_s[smp][k];
            const uint2 u = *(const uint2*)(vb2 + k * 256 + ((2 * d0) ^ ((k & 7) << 4)));
            s0 = fmaf(av, bf_lo(u.x), s0);
            s1 = fmaf(av, bf_hi(u.x), s1);
            s2 = fmaf(av, bf_lo(u.y), s2);
            s3 = fmaf(av, bf_hi(u.y), s3);
        }
        uint2 pk;
        pk.x = (unsigned)f2bf(s0) | ((unsigned)f2bf(s1) << 16);
        pk.y = (unsigned)f2bf(s2) | ((unsigned)f2bf(s3) << 16);
        *(uint2*)(wsum_g + gsS * KD_ + d0) = pk;
    }
}

// MLP tail on MFMA: 32 samples/block, 512 threads (8 waves, n-split).
// Grid B/32 = 512 blocks -> 2 blocks/CU x 8 waves = 16 waves/CU of TLP.
__global__ __launch_bounds__(512) void cdm_mlp(
    const unsigned short* __restrict__ wsum_g,
    const unsigned short* __restrict__ m1f, const unsigned short* __restrict__ m2f,
    const float* __restrict__ mb1, const float* __restrict__ mb2,
    const float* __restrict__ M3, const float* __restrict__ mb3,
    float* __restrict__ out_scores)
{
    const int tid = threadIdx.x, lane = tid & 63, w = tid >> 6;   // w in 0..7
    const int S0 = blockIdx.x * 32;
    const int lr = lane & 15, g = lane >> 4;

    __shared__ unsigned short h1_s[32][HID_];  // 16 KB, 512B rows, swizzled
    __shared__ float sc_s[8][32];              // 1 KB

    // ---- pass 1: h1 = relu(ws @ M1 + mb1); wave w owns cols [32w, 32w+32) ----
    short8_t Aw[2][4];
#pragma unroll
    for (int m = 0; m < 2; ++m)
#pragma unroll
        for (int s = 0; s < 4; ++s)
            Aw[m][s] = *(const short8_t*)(wsum_g + (S0 + m * 16 + lr) * KD_
                                          + s * 32 + g * 8);
    short8_t B1r[2][4];
    {
        const short8_t* bf1 = (const short8_t*)m1f;
#pragma unroll
        for (int nn = 0; nn < 2; ++nn)
#pragma unroll
            for (int s = 0; s < 4; ++s)
                B1r[nn][s] = bf1[((w * 2 + nn) * 4 + s) * 64 + lane];
    }
#pragma unroll
    for (int nn = 0; nn < 2; ++nn) {
        f32x4 c0 = {0.f, 0.f, 0.f, 0.f}, c1 = {0.f, 0.f, 0.f, 0.f};
#pragma unroll
        for (int s = 0; s < 4; ++s) {
            c0 = __builtin_amdgcn_mfma_f32_16x16x32_bf16(Aw[0][s], B1r[nn][s], c0, 0, 0, 0);
            c1 = __builtin_amdgcn_mfma_f32_16x16x32_bf16(Aw[1][s], B1r[nn][s], c1, 0, 0, 0);
        }
        const int col = (w * 2 + nn) * 16 + lr;
        const float bias = mb1[col];
#pragma unroll
        for (int i = 0; i < 4; ++i) {
            const int r0 = g * 4 + i;
            const int r1 = 16 + r0;
            *(unsigned short*)((char*)h1_s + r0 * 512 + ((2 * col) ^ ((r0 & 7) << 4)))
                = f2bf(fmaxf(c0[i] + bias, 0.f));
            *(unsigned short*)((char*)h1_s + r1 * 512 + ((2 * col) ^ ((r0 & 7) << 4)))
                = f2bf(fmaxf(c1[i] + bias, 0.f));
        }
    }
    __syncthreads();

    // ---- pass 2: h2 = relu(h1 @ M2 + mb2) fused M3; wave w owns cols [16w,16w+16) ----
    short8_t B2r[8];
    {
        const short8_t* bf2 = (const short8_t*)m2f;
#pragma unroll
        for (int s = 0; s < 8; ++s)
            B2r[s] = bf2[(w * 8 + s) * 64 + lane];
    }
    f32x4 d0 = {0.f, 0.f, 0.f, 0.f}, d1 = {0.f, 0.f, 0.f, 0.f};
#pragma unroll
    for (int s = 0; s < 8; ++s) {
        const int off = (s * 64 + g * 16) ^ ((lr & 7) << 4);
        const short8_t Ah0 = *(const short8_t*)((const char*)h1_s + lr * 512 + off);
        const short8_t Ah1 = *(const short8_t*)((const char*)h1_s + (16 + lr) * 512 + off);
        d0 = __builtin_amdgcn_mfma_f32_16x16x32_bf16(Ah0, B2r[s], d0, 0, 0, 0);
        d1 = __builtin_amdgcn_mfma_f32_16x16x32_bf16(Ah1, B2r[s], d1, 0, 0, 0);
    }
    {
        const int col = w * 16 + lr;
        const float bb = mb2[col], m3v = M3[col];
        float part0[4], part1[4];
#pragma unroll
        for (int i = 0; i < 4; ++i) {
            part0[i] = fmaxf(d0[i] + bb, 0.f) * m3v;
            part1[i] = fmaxf(d1[i] + bb, 0.f) * m3v;
        }
#pragma unroll
        for (int i = 0; i < 4; ++i) {
#pragma unroll
            for (int q = 1; q <= 8; q <<= 1) {
                part0[i] += __shfl_xor(part0[i], q);
                part1[i] += __shfl_xor(part1[i], q);
            }
        }
        if (lr == 0) {
#pragma unroll
            for (int i = 0; i < 4; ++i) {
                sc_s[w][g * 4 + i]      = part0[i];
                sc_s[w][16 + g * 4 + i] = part1[i];
            }
        }
    }
    __syncthreads();
    if (tid < 32) {
        const float sc = sc_s[0][tid] + sc_s[1][tid] + sc_s[2][tid] + sc_s[3][tid]
                       + sc_s[4][tid] + sc_s[5][tid] + sc_s[6][tid] + sc_s[7][tid] + mb3[0];
        out_scores[S0 + tid] = 1.f / (1.f + __expf(-sc));
    }
}

extern "C" void kernel_launch(void* const* d_in, const int* in_sizes, int n_in,
                              void* d_out, int out_size, void* d_ws, size_t ws_size,
                              hipStream_t stream) {
    const int*   stu = (const int*)d_in[0];
    const int*   kpi = (const int*)d_in[1];
    const int*   kpl = (const int*)d_in[2];
    const float* emb = (const float*)d_in[3];
    const float* W1  = (const float*)d_in[4];
    const float* b1  = (const float*)d_in[5];
    const float* w2  = (const float*)d_in[6];
    const float* b2  = (const float*)d_in[7];
    const float* M1  = (const float*)d_in[8];
    const float* mb1 = (const float*)d_in[9];
    const float* M2  = (const float*)d_in[10];
    const float* mb2 = (const float*)d_in[11];
    const float* M3  = (const float*)d_in[12];
    const float* mb3 = (const float*)d_in[13];
    const int B = in_sizes[0];

    float* out_scores = (float*)d_out;
    float* out_att    = out_scores + B;

    unsigned short* w1f  = (unsigned short*)d_ws;       // 64 KB
    unsigned short* m1f  = w1f + 32768;                 // 64 KB
    unsigned short* m2f  = m1f + 32768;                 // 64 KB
    unsigned short* wsum = m2f + 32768;                 // B*128 bf16 = 4 MB

    prep_frags<<<384, 256, 0, stream>>>(W1, M1, M2, w1f, m1f, m2f);
    cdm_attn<<<B / 8, 256, 0, stream>>>(stu, kpi, kpl, emb, w1f, b1, w2, b2,
                                        out_att, wsum);
    cdm_mlp<<<B / 32, 512, 0, stream>>>(wsum, m1f, m2f, mb1, mb2, M3, mb3, out_scores);
}